// Round 1
// baseline (224.037 us; speedup 1.0000x reference)
//
#include <hip/hip_runtime.h>
#include <hip/hip_fp16.h>

#define NB 32
#define NN 1024

// ---------------- ws layout (in floats unless noted) ----------------
// d      : 0          (32768)   = rsqrt degree, [B,N]
// stats  : 32768      (16384)   = 8 passes x {sum[1024], sumsq[1024]}
// xw1    : 49152      (131072)  = x @ W1, [B,N,4]
// Y[0..7]: 180224 ...  raw relu outputs per pass
// anorm  : byte off 3866624, 32*1024*1024 halves (64 MB)
static const size_t F_D     = 0;
static const size_t F_STATS = 32768;
static const size_t F_XW1   = 49152;
static const size_t F_Y0    = 180224;
static const size_t ANORM_BYTE_OFF = 3866624;
static const size_t WS_NEED_HALF   = ANORM_BYTE_OFF + (size_t)NB*NN*NN*2;

// ------------------------------------------------------------------
// K0: degree + XW1 precompute + stats zero
// grid: [0,8192) degree rows (4 rows/block, 1 wave each)
//       [8192,8320) xw1 (1 node/thread)
//       [8320,8384) zero stats
__global__ __launch_bounds__(256)
void k0_prep(const float* __restrict__ adj, const float* __restrict__ x,
             const float* __restrict__ W1, float* __restrict__ dd,
             float* __restrict__ xw1, float* __restrict__ stats)
{
    const int tid = threadIdx.x;
    const int bx  = blockIdx.x;
    if (bx < 8192) {
        const int lane = tid & 63, wid = tid >> 6;
        const int row = bx * 4 + wid;          // b*1024+n
        const int n = row & (NN - 1);
        const float4* arow = (const float4*)(adj + (size_t)row * NN);
        float s = 0.f;
        #pragma unroll
        for (int it = 0; it < 4; ++it) {
            float4 v = arow[lane + it * 64];
            int k0 = (lane + it * 64) * 4;
            s += (k0 + 0 == n) ? 1.f : v.x;
            s += (k0 + 1 == n) ? 1.f : v.y;
            s += (k0 + 2 == n) ? 1.f : v.z;
            s += (k0 + 3 == n) ? 1.f : v.w;
        }
        #pragma unroll
        for (int m = 1; m < 64; m <<= 1) s += __shfl_xor(s, m);
        if (lane == 0) dd[row] = rsqrtf(fmaxf(s, 1.f));
    } else if (bx < 8320) {
        const int id = (bx - 8192) * 256 + tid;   // b*1024+k
        const float4* xr = (const float4*)(x + (size_t)id * 32);
        float in[32];
        #pragma unroll
        for (int i = 0; i < 8; ++i) {
            float4 v = xr[i];
            in[4*i] = v.x; in[4*i+1] = v.y; in[4*i+2] = v.z; in[4*i+3] = v.w;
        }
        float o[4] = {0.f, 0.f, 0.f, 0.f};
        #pragma unroll
        for (int i = 0; i < 32; ++i)
            #pragma unroll
            for (int c = 0; c < 4; ++c) o[c] += in[i] * W1[i*4 + c];
        *(float4*)(xw1 + (size_t)id * 4) = make_float4(o[0], o[1], o[2], o[3]);
    } else {
        const int id = (bx - 8320) * 256 + tid;   // < 16384
        stats[id] = 0.f;
    }
}

// ------------------------------------------------------------------
// Pass kernel. MODE 0: read adj fp32, write anorm fp16 (pass 1, half path)
//              MODE 1: read anorm fp16 (passes 2-8, half path)
//              MODE 2: read adj fp32, fold d in prologue (fallback path)
// CIN1==0 -> prologue reads precomputed xw1 (pass 1). Else BN-normalize
// src1 (+optional src2) and multiply by W.
template<int MODE, int CIN1, int CIN2, int COUT>
__global__ __launch_bounds__(512)
void pass_kernel(const float* __restrict__ adj,
                 const __half* __restrict__ anorm_r,
                 __half* __restrict__ anorm_w,
                 const float* __restrict__ dd,
                 const float* __restrict__ xw1,
                 const float* __restrict__ src1, const float* __restrict__ st1,
                 const float* __restrict__ src2, const float* __restrict__ st2,
                 const float* __restrict__ W, const float* __restrict__ bias,
                 float* __restrict__ Y, float* __restrict__ stout)
{
    __shared__ float XWt[COUT][NN];
    __shared__ float dl[NN];
    const int tid  = threadIdx.x;
    const int b    = blockIdx.x >> 5;          // 32 tiles per batch
    const int tile = (blockIdx.x & 31) * 32;

    // ---- prologue: build XWt (and dl for MODE0) ----
    for (int k = tid; k < NN; k += 512) {
        float xw[COUT];
        if constexpr (CIN1 == 0) {
            const float4 v = *(const float4*)(xw1 + ((size_t)b*NN + k) * 4);
            xw[0] = v.x; xw[1] = v.y; xw[2] = v.z; xw[3] = v.w;
        } else {
            float in[CIN1 + CIN2];
            {
                const float cnt = 1.f / (32.f * CIN1);
                float m  = st1[k] * cnt;
                float ms = st1[NN + k] * cnt;
                float iv = rsqrtf(ms - m*m + 1e-5f);
                const float* p = src1 + ((size_t)b*NN + k) * CIN1;
                #pragma unroll
                for (int i = 0; i < CIN1; ++i) in[i] = (p[i] - m) * iv;
            }
            if constexpr (CIN2 > 0) {
                const float cnt = 1.f / (32.f * CIN2);
                float m  = st2[k] * cnt;
                float ms = st2[NN + k] * cnt;
                float iv = rsqrtf(ms - m*m + 1e-5f);
                const float* p = src2 + ((size_t)b*NN + k) * CIN2;
                #pragma unroll
                for (int i = 0; i < CIN2; ++i) in[CIN1 + i] = (p[i] - m) * iv;
            }
            #pragma unroll
            for (int c = 0; c < COUT; ++c) {
                float s = 0.f;
                #pragma unroll
                for (int i = 0; i < CIN1 + CIN2; ++i) s += in[i] * W[i*COUT + c];
                xw[c] = s;
            }
        }
        float dk = (MODE == 2) ? dd[(size_t)b*NN + k] : 1.f;
        #pragma unroll
        for (int c = 0; c < COUT; ++c) XWt[c][k] = xw[c] * dk;
        if constexpr (MODE == 0) dl[k] = dd[(size_t)b*NN + k];
    }
    __syncthreads();

    // ---- main: 8 waves x 4 jammed rows ----
    const int lane = tid & 63, wid = tid >> 6;
    const int r0 = tile + wid * 4;
    float acc[4][COUT];
    #pragma unroll
    for (int j = 0; j < 4; ++j)
        #pragma unroll
        for (int c = 0; c < COUT; ++c) acc[j][c] = 0.f;
    float dn[4];
    #pragma unroll
    for (int j = 0; j < 4; ++j)
        dn[j] = (MODE != 1) ? dd[(size_t)b*NN + r0 + j] : 1.f;
    size_t rb[4];
    #pragma unroll
    for (int j = 0; j < 4; ++j) rb[j] = ((size_t)(b*NN + r0 + j)) * NN;

    #pragma unroll 4
    for (int it = 0; it < 16; ++it) {
        const int k = lane + it * 64;
        float xv[COUT];
        #pragma unroll
        for (int c = 0; c < COUT; ++c) xv[c] = XWt[c][k];
        float dk = 0.f;
        if constexpr (MODE == 0) dk = dl[k];
        #pragma unroll
        for (int j = 0; j < 4; ++j) {
            if constexpr (MODE == 1) {
                float a = __half2float(anorm_r[rb[j] + k]);
                #pragma unroll
                for (int c = 0; c < COUT; ++c) acc[j][c] += a * xv[c];
            } else {
                float a = adj[rb[j] + k];
                if (k == r0 + j) a = 1.f;
                if constexpr (MODE == 0) {
                    float t = a * dk;
                    anorm_w[rb[j] + k] = __float2half(t * dn[j]);
                    #pragma unroll
                    for (int c = 0; c < COUT; ++c) acc[j][c] += t * xv[c];
                } else {
                    #pragma unroll
                    for (int c = 0; c < COUT; ++c) acc[j][c] += a * xv[c];
                }
            }
        }
    }

    // ---- epilogue: wave reduce, relu, store Y, atomic BN stats ----
    #pragma unroll
    for (int j = 0; j < 4; ++j) {
        #pragma unroll
        for (int c = 0; c < COUT; ++c) {
            float v = acc[j][c];
            #pragma unroll
            for (int m = 1; m < 64; m <<= 1) v += __shfl_xor(v, m);
            acc[j][c] = v;
        }
        if (lane == 0) {
            float s = 0.f, q = 0.f;
            #pragma unroll
            for (int c = 0; c < COUT; ++c) {
                float y = acc[j][c] * dn[j] + bias[c];
                y = fmaxf(y, 0.f);
                Y[((size_t)(b*NN + r0 + j)) * COUT + c] = y;
                s += y; q += y * y;
            }
            atomicAdd(stout + (r0 + j), s);
            atomicAdd(stout + NN + (r0 + j), q);
        }
    }
}

// ------------------------------------------------------------------
// K10: 4 max-pools over nodes + final linear [B,24]@[24,3]+bl
__global__ __launch_bounds__(256)
void k_final(const float* __restrict__ Y1, const float* __restrict__ Y2,
             const float* __restrict__ Y3, const float* __restrict__ Y4,
             const float* __restrict__ Y5, const float* __restrict__ Y6,
             const float* __restrict__ Y7, const float* __restrict__ Y8,
             const float* __restrict__ stats,
             const float* __restrict__ Wl, const float* __restrict__ bl,
             float* __restrict__ out)
{
    const float* Ya[4] = {Y1, Y3, Y5, Y7};
    const float* Yb[4] = {Y2, Y4, Y6, Y8};
    const int b = blockIdx.x, tid = threadIdx.x;
    float mx[24];
    #pragma unroll
    for (int i = 0; i < 24; ++i) mx[i] = -3.4e38f;

    for (int n = tid; n < NN; n += 256) {
        #pragma unroll
        for (int g = 0; g < 4; ++g) {
            {
                const float* st = stats + (size_t)(2*g) * 2048;
                const float cnt = 1.f / 128.f;
                float m  = st[n] * cnt;
                float ms = st[NN + n] * cnt;
                float iv = rsqrtf(ms - m*m + 1e-5f);
                const float4 v = *(const float4*)(Ya[g] + ((size_t)b*NN + n) * 4);
                mx[g*6+0] = fmaxf(mx[g*6+0], (v.x - m) * iv);
                mx[g*6+1] = fmaxf(mx[g*6+1], (v.y - m) * iv);
                mx[g*6+2] = fmaxf(mx[g*6+2], (v.z - m) * iv);
                mx[g*6+3] = fmaxf(mx[g*6+3], (v.w - m) * iv);
            }
            {
                const float* st = stats + (size_t)(2*g+1) * 2048;
                const float cnt = 1.f / 64.f;
                float m  = st[n] * cnt;
                float ms = st[NN + n] * cnt;
                float iv = rsqrtf(ms - m*m + 1e-5f);
                const float2 v = *(const float2*)(Yb[g] + ((size_t)b*NN + n) * 2);
                mx[g*6+4] = fmaxf(mx[g*6+4], (v.x - m) * iv);
                mx[g*6+5] = fmaxf(mx[g*6+5], (v.y - m) * iv);
            }
        }
    }
    const int lane = tid & 63, wid = tid >> 6;
    #pragma unroll
    for (int i = 0; i < 24; ++i) {
        float v = mx[i];
        #pragma unroll
        for (int m = 1; m < 64; m <<= 1) v = fmaxf(v, __shfl_xor(v, m));
        mx[i] = v;
    }
    __shared__ float red[4][24];
    __shared__ float pooled[24];
    if (lane == 0) {
        #pragma unroll
        for (int i = 0; i < 24; ++i) red[wid][i] = mx[i];
    }
    __syncthreads();
    if (tid < 24)
        pooled[tid] = fmaxf(fmaxf(red[0][tid], red[1][tid]),
                            fmaxf(red[2][tid], red[3][tid]));
    __syncthreads();
    if (tid < 3) {
        float s = bl[tid];
        #pragma unroll
        for (int c = 0; c < 24; ++c) s += pooled[c] * Wl[c*3 + tid];
        out[b*3 + tid] = s;
    }
}

// ------------------------------------------------------------------
extern "C" void kernel_launch(void* const* d_in, const int* in_sizes, int n_in,
                              void* d_out, int out_size, void* d_ws, size_t ws_size,
                              hipStream_t stream)
{
    const float* x   = (const float*)d_in[0];
    const float* adj = (const float*)d_in[1];
    const float* W1  = (const float*)d_in[2];
    const float* b1  = (const float*)d_in[3];
    const float* W2  = (const float*)d_in[4];
    const float* b2  = (const float*)d_in[5];
    const float* W3  = (const float*)d_in[6];
    const float* b3  = (const float*)d_in[7];
    const float* W5  = (const float*)d_in[8];
    const float* b5  = (const float*)d_in[9];
    const float* W7  = (const float*)d_in[10];
    const float* b7  = (const float*)d_in[11];
    const float* Wl  = (const float*)d_in[12];
    const float* bl  = (const float*)d_in[13];
    float* out = (float*)d_out;

    float* wsf   = (float*)d_ws;
    float* dd    = wsf + F_D;
    float* stats = wsf + F_STATS;
    float* xw1   = wsf + F_XW1;
    float* Y[8];
    {
        size_t off = F_Y0;
        const int cs[8] = {4, 2, 4, 2, 4, 2, 4, 2};
        for (int i = 0; i < 8; ++i) { Y[i] = wsf + off; off += (size_t)NB*NN*cs[i]; }
    }
    __half* anorm = (__half*)((char*)d_ws + ANORM_BYTE_OFF);
    const bool use_half = (ws_size >= WS_NEED_HALF);

    k0_prep<<<8384, 256, 0, stream>>>(adj, x, W1, dd, xw1, stats);

    #define STT(i) (stats + (i)*2048)
    const dim3 pg(1024), pb(512);
    if (use_half) {
        pass_kernel<0,0,0,4><<<pg, pb, 0, stream>>>(adj, nullptr, anorm, dd, xw1,
            nullptr, nullptr, nullptr, nullptr, nullptr, b1, Y[0], STT(0));
        pass_kernel<1,4,0,2><<<pg, pb, 0, stream>>>(nullptr, anorm, nullptr, dd, nullptr,
            Y[0], STT(0), nullptr, nullptr, W2, b2, Y[1], STT(1));
        pass_kernel<1,4,2,4><<<pg, pb, 0, stream>>>(nullptr, anorm, nullptr, dd, nullptr,
            Y[0], STT(0), Y[1], STT(1), W3, b3, Y[2], STT(2));
        pass_kernel<1,4,0,2><<<pg, pb, 0, stream>>>(nullptr, anorm, nullptr, dd, nullptr,
            Y[2], STT(2), nullptr, nullptr, W2, b2, Y[3], STT(3));
        pass_kernel<1,4,2,4><<<pg, pb, 0, stream>>>(nullptr, anorm, nullptr, dd, nullptr,
            Y[2], STT(2), Y[3], STT(3), W5, b5, Y[4], STT(4));
        pass_kernel<1,4,0,2><<<pg, pb, 0, stream>>>(nullptr, anorm, nullptr, dd, nullptr,
            Y[4], STT(4), nullptr, nullptr, W2, b2, Y[5], STT(5));
        pass_kernel<1,4,2,4><<<pg, pb, 0, stream>>>(nullptr, anorm, nullptr, dd, nullptr,
            Y[4], STT(4), Y[5], STT(5), W7, b7, Y[6], STT(6));
        pass_kernel<1,4,0,2><<<pg, pb, 0, stream>>>(nullptr, anorm, nullptr, dd, nullptr,
            Y[6], STT(6), nullptr, nullptr, W2, b2, Y[7], STT(7));
    } else {
        pass_kernel<2,0,0,4><<<pg, pb, 0, stream>>>(adj, nullptr, nullptr, dd, xw1,
            nullptr, nullptr, nullptr, nullptr, nullptr, b1, Y[0], STT(0));
        pass_kernel<2,4,0,2><<<pg, pb, 0, stream>>>(adj, nullptr, nullptr, dd, nullptr,
            Y[0], STT(0), nullptr, nullptr, W2, b2, Y[1], STT(1));
        pass_kernel<2,4,2,4><<<pg, pb, 0, stream>>>(adj, nullptr, nullptr, dd, nullptr,
            Y[0], STT(0), Y[1], STT(1), W3, b3, Y[2], STT(2));
        pass_kernel<2,4,0,2><<<pg, pb, 0, stream>>>(adj, nullptr, nullptr, dd, nullptr,
            Y[2], STT(2), nullptr, nullptr, W2, b2, Y[3], STT(3));
        pass_kernel<2,4,2,4><<<pg, pb, 0, stream>>>(adj, nullptr, nullptr, dd, nullptr,
            Y[2], STT(2), Y[3], STT(3), W5, b5, Y[4], STT(4));
        pass_kernel<2,4,0,2><<<pg, pb, 0, stream>>>(adj, nullptr, nullptr, dd, nullptr,
            Y[4], STT(4), nullptr, nullptr, W2, b2, Y[5], STT(5));
        pass_kernel<2,4,2,4><<<pg, pb, 0, stream>>>(adj, nullptr, nullptr, dd, nullptr,
            Y[4], STT(4), Y[5], STT(5), W7, b7, Y[6], STT(6));
        pass_kernel<2,4,0,2><<<pg, pb, 0, stream>>>(adj, nullptr, nullptr, dd, nullptr,
            Y[6], STT(6), nullptr, nullptr, W2, b2, Y[7], STT(7));
    }
    #undef STT

    k_final<<<32, 256, 0, stream>>>(Y[0], Y[1], Y[2], Y[3], Y[4], Y[5], Y[6], Y[7],
                                    stats, Wl, bl, out);
}

// Round 2
// 219.332 us; speedup vs baseline: 1.0215x; 1.0215x over previous
//
#include <hip/hip_runtime.h>
#include <hip/hip_fp16.h>

#define NB 32
#define NN 1024

// ---------------- ws layout (floats unless noted) ----------------
static const size_t F_D     = 0;        // 32768  : rsqrt degree [B,N]
static const size_t F_STATS = 32768;    // 16384  : 8 x {sum[1024], sumsq[1024]}
static const size_t F_XW1   = 49152;    // 131072 : x @ W1  [B,N,4]
static const size_t F_Y0    = 180224;   // raw relu outputs, 8 passes
static const size_t AH_BYTE_OFF = 3866624;                   // fp16 adj(diag=1), 64MB
static const size_t WS_NEED_HALF = AH_BYTE_OFF + (size_t)NB*NN*NN*2;

// ------------------------------------------------------------------
// K0: degree (+ write fp16 ah) + XW1 precompute + stats zero
__global__ __launch_bounds__(256)
void k0_prep(const float* __restrict__ adj, const float* __restrict__ x,
             const float* __restrict__ W1, float* __restrict__ dd,
             float* __restrict__ xw1, float* __restrict__ stats,
             __half* __restrict__ ahw)
{
    const int tid = threadIdx.x;
    const int bx  = blockIdx.x;
    if (bx < 8192) {
        const int lane = tid & 63, wid = tid >> 6;
        const int row = bx * 4 + wid;          // b*1024+n
        const int n = row & (NN - 1);
        const float4* arow = (const float4*)(adj + (size_t)row * NN);
        uint2* hrow = (uint2*)(ahw + (size_t)row * NN);
        float s = 0.f;
        #pragma unroll
        for (int it = 0; it < 4; ++it) {
            const int idx = lane + it * 64;
            float4 v = arow[idx];
            const int k0 = idx * 4;
            v.x = (k0 + 0 == n) ? 1.f : v.x;
            v.y = (k0 + 1 == n) ? 1.f : v.y;
            v.z = (k0 + 2 == n) ? 1.f : v.z;
            v.w = (k0 + 3 == n) ? 1.f : v.w;
            s += v.x + v.y + v.z + v.w;
            if (ahw) {
                __half2 h01 = __floats2half2_rn(v.x, v.y);
                __half2 h23 = __floats2half2_rn(v.z, v.w);
                uint2 u;
                u.x = *(unsigned*)&h01;
                u.y = *(unsigned*)&h23;
                hrow[idx] = u;
            }
        }
        #pragma unroll
        for (int m = 1; m < 64; m <<= 1) s += __shfl_xor(s, m);
        if (lane == 0) dd[row] = rsqrtf(fmaxf(s, 1.f));
    } else if (bx < 8320) {
        const int id = (bx - 8192) * 256 + tid;   // b*1024+k
        const float4* xr = (const float4*)(x + (size_t)id * 32);
        float in[32];
        #pragma unroll
        for (int i = 0; i < 8; ++i) {
            float4 v = xr[i];
            in[4*i] = v.x; in[4*i+1] = v.y; in[4*i+2] = v.z; in[4*i+3] = v.w;
        }
        float o[4] = {0.f, 0.f, 0.f, 0.f};
        #pragma unroll
        for (int i = 0; i < 32; ++i)
            #pragma unroll
            for (int c = 0; c < 4; ++c) o[c] += in[i] * W1[i*4 + c];
        *(float4*)(xw1 + (size_t)id * 4) = make_float4(o[0], o[1], o[2], o[3]);
    } else {
        const int id = (bx - 8320) * 256 + tid;   // < 16384
        stats[id] = 0.f;
    }
}

// ------------------------------------------------------------------
// Pass kernel: Y = relu(Anorm @ XW + b), Anorm = d[r] * ah[r][k] * d[k].
// ah holds raw adj with diag=1 (fp16 when HALFA, else read adj fp32 + diag fix).
// d[k] is folded into the LDS XW tile; d[r] applied at the epilogue.
// CIN1==0 -> prologue reads precomputed xw1; else BN-normalize src1(+src2), @W.
// LDS XW layout padded: word index m(k) = k + 4*(k>>5)  -> conflict-free b128.
template<bool HALFA, int CIN1, int CIN2, int COUT>
__global__ __launch_bounds__(512)
void pass_kernel(const float* __restrict__ adj,
                 const __half* __restrict__ ah,
                 const float* __restrict__ dd,
                 const float* __restrict__ xw1,
                 const float* __restrict__ src1, const float* __restrict__ st1,
                 const float* __restrict__ src2, const float* __restrict__ st2,
                 const float* __restrict__ W, const float* __restrict__ bias,
                 float* __restrict__ Y, float* __restrict__ stout)
{
    __shared__ float XP[COUT][NN + (NN/32)*4];   // 1152 words per c
    const int tid  = threadIdx.x;
    const int b    = blockIdx.x >> 5;            // 32 tiles per batch
    const int tile = (blockIdx.x & 31) * 32;

    // ---- prologue: build XW tile (d[k] folded) ----
    for (int k = tid; k < NN; k += 512) {
        float xw[COUT];
        if constexpr (CIN1 == 0) {
            const float4 v = *(const float4*)(xw1 + ((size_t)b*NN + k) * 4);
            xw[0] = v.x; xw[1] = v.y; xw[2] = v.z; xw[3] = v.w;
        } else {
            float in[CIN1 + CIN2];
            {
                const float cnt = 1.f / (32.f * CIN1);
                float m  = st1[k] * cnt;
                float ms = st1[NN + k] * cnt;
                float iv = rsqrtf(ms - m*m + 1e-5f);
                const float4 v = *(const float4*)(src1 + ((size_t)b*NN + k) * CIN1);
                in[0] = (v.x - m) * iv; in[1] = (v.y - m) * iv;
                in[2] = (v.z - m) * iv; in[3] = (v.w - m) * iv;
            }
            if constexpr (CIN2 > 0) {
                const float cnt = 1.f / (32.f * CIN2);
                float m  = st2[k] * cnt;
                float ms = st2[NN + k] * cnt;
                float iv = rsqrtf(ms - m*m + 1e-5f);
                const float2 v = *(const float2*)(src2 + ((size_t)b*NN + k) * CIN2);
                in[CIN1 + 0] = (v.x - m) * iv;
                in[CIN1 + 1] = (v.y - m) * iv;
            }
            #pragma unroll
            for (int c = 0; c < COUT; ++c) {
                float s = 0.f;
                #pragma unroll
                for (int i = 0; i < CIN1 + CIN2; ++i) s += in[i] * W[i*COUT + c];
                xw[c] = s;
            }
        }
        const float dk = dd[(size_t)b*NN + k];
        const int mk = k + ((k >> 5) << 2);
        #pragma unroll
        for (int c = 0; c < COUT; ++c) XP[c][mk] = xw[c] * dk;
    }
    __syncthreads();

    // ---- main: 8 waves x 4 jammed rows, 16B loads ----
    const int lane = tid & 63, wid = tid >> 6;
    const int r0 = tile + wid * 4;
    float acc[4][COUT];
    #pragma unroll
    for (int j = 0; j < 4; ++j)
        #pragma unroll
        for (int c = 0; c < COUT; ++c) acc[j][c] = 0.f;
    float dn[4];
    size_t rb[4];
    #pragma unroll
    for (int j = 0; j < 4; ++j) {
        dn[j] = dd[(size_t)b*NN + r0 + j];
        rb[j] = ((size_t)(b*NN + r0 + j)) * NN;
    }

    if constexpr (HALFA) {
        #pragma unroll
        for (int it = 0; it < 2; ++it) {
            const int kw = 8 * (lane + 64 * it);
            const int mb = kw + ((kw >> 5) << 2);
            float xwv[COUT][8];
            #pragma unroll
            for (int c = 0; c < COUT; ++c) {
                const float4 lo = *(const float4*)&XP[c][mb];
                const float4 hi = *(const float4*)&XP[c][mb + 4];
                xwv[c][0]=lo.x; xwv[c][1]=lo.y; xwv[c][2]=lo.z; xwv[c][3]=lo.w;
                xwv[c][4]=hi.x; xwv[c][5]=hi.y; xwv[c][6]=hi.z; xwv[c][7]=hi.w;
            }
            #pragma unroll
            for (int j = 0; j < 4; ++j) {
                const float4 rv = *(const float4*)(ah + rb[j] + kw);
                const __half2* hp = (const __half2*)&rv;
                float a8[8];
                #pragma unroll
                for (int q = 0; q < 4; ++q) {
                    const float2 f = __half22float2(hp[q]);
                    a8[2*q] = f.x; a8[2*q+1] = f.y;
                }
                #pragma unroll
                for (int c = 0; c < COUT; ++c) {
                    float s = acc[j][c];
                    #pragma unroll
                    for (int q = 0; q < 8; ++q) s = fmaf(a8[q], xwv[c][q], s);
                    acc[j][c] = s;
                }
            }
        }
    } else {
        #pragma unroll
        for (int it = 0; it < 4; ++it) {
            const int kw = 4 * (lane + 64 * it);
            const int mb = kw + ((kw >> 5) << 2);
            float xwv[COUT][4];
            #pragma unroll
            for (int c = 0; c < COUT; ++c) {
                const float4 v = *(const float4*)&XP[c][mb];
                xwv[c][0]=v.x; xwv[c][1]=v.y; xwv[c][2]=v.z; xwv[c][3]=v.w;
            }
            #pragma unroll
            for (int j = 0; j < 4; ++j) {
                const int rr = r0 + j;
                float4 a = *(const float4*)(adj + rb[j] + kw);
                a.x = (kw + 0 == rr) ? 1.f : a.x;
                a.y = (kw + 1 == rr) ? 1.f : a.y;
                a.z = (kw + 2 == rr) ? 1.f : a.z;
                a.w = (kw + 3 == rr) ? 1.f : a.w;
                #pragma unroll
                for (int c = 0; c < COUT; ++c) {
                    float s = acc[j][c];
                    s = fmaf(a.x, xwv[c][0], s);
                    s = fmaf(a.y, xwv[c][1], s);
                    s = fmaf(a.z, xwv[c][2], s);
                    s = fmaf(a.w, xwv[c][3], s);
                    acc[j][c] = s;
                }
            }
        }
    }

    // ---- epilogue: wave reduce, relu, store Y, atomic BN stats ----
    #pragma unroll
    for (int j = 0; j < 4; ++j) {
        #pragma unroll
        for (int c = 0; c < COUT; ++c) {
            float v = acc[j][c];
            #pragma unroll
            for (int m = 1; m < 64; m <<= 1) v += __shfl_xor(v, m);
            acc[j][c] = v;
        }
        if (lane == 0) {
            float s = 0.f, q = 0.f;
            #pragma unroll
            for (int c = 0; c < COUT; ++c) {
                float y = acc[j][c] * dn[j] + bias[c];
                y = fmaxf(y, 0.f);
                Y[((size_t)(b*NN + r0 + j)) * COUT + c] = y;
                s += y; q += y * y;
            }
            atomicAdd(stout + (r0 + j), s);
            atomicAdd(stout + NN + (r0 + j), q);
        }
    }
}

// ------------------------------------------------------------------
// Final: 4 max-pools over nodes + linear [B,24]@[24,3]+bl
__global__ __launch_bounds__(256)
void k_final(const float* __restrict__ Y1, const float* __restrict__ Y2,
             const float* __restrict__ Y3, const float* __restrict__ Y4,
             const float* __restrict__ Y5, const float* __restrict__ Y6,
             const float* __restrict__ Y7, const float* __restrict__ Y8,
             const float* __restrict__ stats,
             const float* __restrict__ Wl, const float* __restrict__ bl,
             float* __restrict__ out)
{
    const float* Ya[4] = {Y1, Y3, Y5, Y7};
    const float* Yb[4] = {Y2, Y4, Y6, Y8};
    const int b = blockIdx.x, tid = threadIdx.x;
    float mx[24];
    #pragma unroll
    for (int i = 0; i < 24; ++i) mx[i] = -3.4e38f;

    for (int n = tid; n < NN; n += 256) {
        #pragma unroll
        for (int g = 0; g < 4; ++g) {
            {
                const float* st = stats + (size_t)(2*g) * 2048;
                const float cnt = 1.f / 128.f;
                float m  = st[n] * cnt;
                float ms = st[NN + n] * cnt;
                float iv = rsqrtf(ms - m*m + 1e-5f);
                const float4 v = *(const float4*)(Ya[g] + ((size_t)b*NN + n) * 4);
                mx[g*6+0] = fmaxf(mx[g*6+0], (v.x - m) * iv);
                mx[g*6+1] = fmaxf(mx[g*6+1], (v.y - m) * iv);
                mx[g*6+2] = fmaxf(mx[g*6+2], (v.z - m) * iv);
                mx[g*6+3] = fmaxf(mx[g*6+3], (v.w - m) * iv);
            }
            {
                const float* st = stats + (size_t)(2*g+1) * 2048;
                const float cnt = 1.f / 64.f;
                float m  = st[n] * cnt;
                float ms = st[NN + n] * cnt;
                float iv = rsqrtf(ms - m*m + 1e-5f);
                const float2 v = *(const float2*)(Yb[g] + ((size_t)b*NN + n) * 2);
                mx[g*6+4] = fmaxf(mx[g*6+4], (v.x - m) * iv);
                mx[g*6+5] = fmaxf(mx[g*6+5], (v.y - m) * iv);
            }
        }
    }
    const int lane = tid & 63, wid = tid >> 6;
    #pragma unroll
    for (int i = 0; i < 24; ++i) {
        float v = mx[i];
        #pragma unroll
        for (int m = 1; m < 64; m <<= 1) v = fmaxf(v, __shfl_xor(v, m));
        mx[i] = v;
    }
    __shared__ float red[4][24];
    __shared__ float pooled[24];
    if (lane == 0) {
        #pragma unroll
        for (int i = 0; i < 24; ++i) red[wid][i] = mx[i];
    }
    __syncthreads();
    if (tid < 24)
        pooled[tid] = fmaxf(fmaxf(red[0][tid], red[1][tid]),
                            fmaxf(red[2][tid], red[3][tid]));
    __syncthreads();
    if (tid < 3) {
        float s = bl[tid];
        #pragma unroll
        for (int c = 0; c < 24; ++c) s += pooled[c] * Wl[c*3 + tid];
        out[b*3 + tid] = s;
    }
}

// ------------------------------------------------------------------
extern "C" void kernel_launch(void* const* d_in, const int* in_sizes, int n_in,
                              void* d_out, int out_size, void* d_ws, size_t ws_size,
                              hipStream_t stream)
{
    const float* x   = (const float*)d_in[0];
    const float* adj = (const float*)d_in[1];
    const float* W1  = (const float*)d_in[2];
    const float* b1  = (const float*)d_in[3];
    const float* W2  = (const float*)d_in[4];
    const float* b2  = (const float*)d_in[5];
    const float* W3  = (const float*)d_in[6];
    const float* b3  = (const float*)d_in[7];
    const float* W5  = (const float*)d_in[8];
    const float* b5  = (const float*)d_in[9];
    const float* W7  = (const float*)d_in[10];
    const float* b7  = (const float*)d_in[11];
    const float* Wl  = (const float*)d_in[12];
    const float* bl  = (const float*)d_in[13];
    float* out = (float*)d_out;

    float* wsf   = (float*)d_ws;
    float* dd    = wsf + F_D;
    float* stats = wsf + F_STATS;
    float* xw1   = wsf + F_XW1;
    float* Y[8];
    {
        size_t off = F_Y0;
        const int cs[8] = {4, 2, 4, 2, 4, 2, 4, 2};
        for (int i = 0; i < 8; ++i) { Y[i] = wsf + off; off += (size_t)NB*NN*cs[i]; }
    }
    __half* ah = (__half*)((char*)d_ws + AH_BYTE_OFF);
    const bool use_half = (ws_size >= WS_NEED_HALF);

    k0_prep<<<8384, 256, 0, stream>>>(adj, x, W1, dd, xw1, stats,
                                      use_half ? ah : nullptr);

    #define STT(i) (stats + (i)*2048)
    const dim3 pg(1024), pb(512);
    if (use_half) {
        pass_kernel<true,0,0,4><<<pg, pb, 0, stream>>>(nullptr, ah, dd, xw1,
            nullptr, nullptr, nullptr, nullptr, nullptr, b1, Y[0], STT(0));
        pass_kernel<true,4,0,2><<<pg, pb, 0, stream>>>(nullptr, ah, dd, nullptr,
            Y[0], STT(0), nullptr, nullptr, W2, b2, Y[1], STT(1));
        pass_kernel<true,4,2,4><<<pg, pb, 0, stream>>>(nullptr, ah, dd, nullptr,
            Y[0], STT(0), Y[1], STT(1), W3, b3, Y[2], STT(2));
        pass_kernel<true,4,0,2><<<pg, pb, 0, stream>>>(nullptr, ah, dd, nullptr,
            Y[2], STT(2), nullptr, nullptr, W2, b2, Y[3], STT(3));
        pass_kernel<true,4,2,4><<<pg, pb, 0, stream>>>(nullptr, ah, dd, nullptr,
            Y[2], STT(2), Y[3], STT(3), W5, b5, Y[4], STT(4));
        pass_kernel<true,4,0,2><<<pg, pb, 0, stream>>>(nullptr, ah, dd, nullptr,
            Y[4], STT(4), nullptr, nullptr, W2, b2, Y[5], STT(5));
        pass_kernel<true,4,2,4><<<pg, pb, 0, stream>>>(nullptr, ah, dd, nullptr,
            Y[4], STT(4), Y[5], STT(5), W7, b7, Y[6], STT(6));
        pass_kernel<true,4,0,2><<<pg, pb, 0, stream>>>(nullptr, ah, dd, nullptr,
            Y[6], STT(6), nullptr, nullptr, W2, b2, Y[7], STT(7));
    } else {
        pass_kernel<false,0,0,4><<<pg, pb, 0, stream>>>(adj, nullptr, dd, xw1,
            nullptr, nullptr, nullptr, nullptr, nullptr, b1, Y[0], STT(0));
        pass_kernel<false,4,0,2><<<pg, pb, 0, stream>>>(adj, nullptr, dd, nullptr,
            Y[0], STT(0), nullptr, nullptr, W2, b2, Y[1], STT(1));
        pass_kernel<false,4,2,4><<<pg, pb, 0, stream>>>(adj, nullptr, dd, nullptr,
            Y[0], STT(0), Y[1], STT(1), W3, b3, Y[2], STT(2));
        pass_kernel<false,4,0,2><<<pg, pb, 0, stream>>>(adj, nullptr, dd, nullptr,
            Y[2], STT(2), nullptr, nullptr, W2, b2, Y[3], STT(3));
        pass_kernel<false,4,2,4><<<pg, pb, 0, stream>>>(adj, nullptr, dd, nullptr,
            Y[2], STT(2), Y[3], STT(3), W5, b5, Y[4], STT(4));
        pass_kernel<false,4,0,2><<<pg, pb, 0, stream>>>(adj, nullptr, dd, nullptr,
            Y[4], STT(4), nullptr, nullptr, W2, b2, Y[5], STT(5));
        pass_kernel<false,4,2,4><<<pg, pb, 0, stream>>>(adj, nullptr, dd, nullptr,
            Y[4], STT(4), Y[5], STT(5), W7, b7, Y[6], STT(6));
        pass_kernel<false,4,0,2><<<pg, pb, 0, stream>>>(adj, nullptr, dd, nullptr,
            Y[6], STT(6), nullptr, nullptr, W2, b2, Y[7], STT(7));
    }
    #undef STT

    k_final<<<32, 256, 0, stream>>>(Y[0], Y[1], Y[2], Y[3], Y[4], Y[5], Y[6], Y[7],
                                    stats, Wl, bl, out);
}